// Round 1
// 2563.377 us; speedup vs baseline: 1.1222x; 1.1222x over previous
//
#include <hip/hip_runtime.h>
#include <hip/hip_bf16.h>

// GNNRecommender: LSTM(20) + content linear + 2x bipartite SAGE (CSR gather) + classifier.
// Round 9: FUSED LSTM. Measured facts: isbf=0, ok32=1 (MFMA 16x16x32_bf16 + LUT proven).
// Round-8 ran 20 separate LSTM step launches, round-tripping h (8MB) + c (32MB R+W)
// through HBM each step (~56MB/step => ~1.9ms of the 2.88ms total). Now: ONE launch,
// c-state in registers (per-wave gate-quad tiling makes i,f,g,o for a (node,j) land in
// the same lane+reg), h in padded LDS, bias folded into MFMA acc init. Removed k_diag
// burn and the 20 no-op VALU launches (fallback is one fused kernel, gated on !ok32).

typedef __bf16 bf16;
typedef __bf16 bf16x2 __attribute__((ext_vector_type(2)));
typedef __bf16 bf16x8 __attribute__((ext_vector_type(8)));
typedef float floatx4 __attribute__((ext_vector_type(4)));

#define N_NODES 32768
#define NMASK 32767
#define T_STEPS 20
#define EMBD 64
#define HD 128
#define G4 512   // 4*H gate width
#define XPAD 72  // xtile row stride (bf16): 144B => start banks spread, conflict-free b128
#define HPAD 136 // h_lds row stride (bf16): 272B => same bank spread property, 16B aligned

__device__ __forceinline__ float sigf(float x) { return 1.f / (1.f + __expf(-x)); }

__device__ __forceinline__ float ldf(const void* p, size_t i, int isbf) {
  return isbf ? (float)((const bf16*)p)[i] : ((const float*)p)[i];
}

// exact-integer probe matrices (small ints => exact in bf16 and fp32)
__device__ __forceinline__ float A3f(int m, int k) { return (float)((m * 37 + k * 11) % 13 - 6); }
__device__ __forceinline__ float B3f(int k, int n) { return (float)((k * 7 + n * 29) % 11 - 5); }
__device__ __forceinline__ unsigned short bfb(float f) {
  return (unsigned short)(__float_as_uint(f) >> 16);
}

// ---------------- dtype probe: flag=1 bf16, 0 fp32 ----------------
__global__ void k_detect(const unsigned* __restrict__ x, int* __restrict__ flag)
{
  if (threadIdx.x == 0 && blockIdx.x == 0) {
    int cnt = 0;
    for (int i = 0; i < 256; ++i) {
      const unsigned w = x[i];
      const unsigned e0 = (w >> 7) & 0xffu;
      const unsigned e1 = (w >> 23) & 0xffu;
      const bool ok0 = (e0 >= 90u && e0 <= 141u) || ((w & 0x7fffu) == 0u);
      const bool ok1 = (e1 >= 90u && e1 <= 141u) || (((w >> 16) & 0x7fffu) == 0u);
      if (ok0 && ok1) ++cnt;
    }
    *flag = (cnt >= 200) ? 1 : 0;
  }
}

__global__ __launch_bounds__(256) void k_zero_int(int* __restrict__ p, int n)
{
  const int i = blockIdx.x * 256 + threadIdx.x;
  if (i < n) p[i] = 0;
}

// ================= MFMA probe (verified working; ok32=1 measured) =================
__global__ __launch_bounds__(64) void k_probe(
    unsigned short* __restrict__ fr, int* __restrict__ lut32, int* __restrict__ ok32p)
{
  __shared__ int seen[256];
  __shared__ int fail;
  const int lane = threadIdx.x;
  const int mrow = lane & 15, quad = lane >> 4;
  const floatx4 vz = {0.f, 0.f, 0.f, 0.f};

  unsigned short* fa1 = fr + 0 * 512;
  unsigned short* fb1 = fr + 1 * 512;
  unsigned short* fa2 = fr + 2 * 512;
  unsigned short* fb2 = fr + 3 * 512;
  unsigned short* fa3 = fr + 4 * 512;
  unsigned short* fb3 = fr + 5 * 512;
  for (int j = 0; j < 8; ++j) {
    fa1[lane * 8 + j] = bfb((float)(mrow + 1));
    fb1[lane * 8 + j] = bfb(1.0f);
    fa2[lane * 8 + j] = bfb(1.0f);
    fb2[lane * 8 + j] = bfb((float)(mrow + 1));
    fa3[lane * 8 + j] = bfb(A3f(mrow, quad * 8 + j));
    fb3[lane * 8 + j] = bfb(B3f(quad * 8 + j, mrow));
  }
  for (int i = lane; i < 256; i += 64) seen[i] = 0;
  if (lane == 0) fail = 0;
  __syncthreads();
  {
    bf16x8 a1 = *(const bf16x8*)(fa1 + lane * 8);
    bf16x8 b1 = *(const bf16x8*)(fb1 + lane * 8);
    bf16x8 a2 = *(const bf16x8*)(fa2 + lane * 8);
    bf16x8 b2 = *(const bf16x8*)(fb2 + lane * 8);
    bf16x8 a3 = *(const bf16x8*)(fa3 + lane * 8);
    bf16x8 b3 = *(const bf16x8*)(fb3 + lane * 8);
    floatx4 r1 = __builtin_amdgcn_mfma_f32_16x16x32_bf16(a1, b1, vz, 0, 0, 0);
    floatx4 r2 = __builtin_amdgcn_mfma_f32_16x16x32_bf16(a2, b2, vz, 0, 0, 0);
    floatx4 r3 = __builtin_amdgcn_mfma_f32_16x16x32_bf16(a3, b3, vz, 0, 0, 0);
    #pragma unroll
    for (int reg = 0; reg < 4; ++reg) {
      const int m = __float2int_rn(r1[reg] * (1.f / 32.f)) - 1;
      const int n = __float2int_rn(r2[reg] * (1.f / 32.f)) - 1;
      bool good = (m >= 0 && m < 16 && n >= 0 && n < 16)
               && fabsf(r1[reg] - 32.f * (m + 1)) < 0.5f
               && fabsf(r2[reg] - 32.f * (n + 1)) < 0.5f;
      if (good) {
        float c3 = 0.f;
        for (int k = 0; k < 32; ++k) c3 += A3f(m, k) * B3f(k, n);
        good = fabsf(r3[reg] - c3) < 0.5f;
      }
      if (good) {
        atomicAdd(&seen[m * 16 + n], 1);
        lut32[lane * 4 + reg] = (m << 4) | n;
      } else fail = 1;
    }
  }
  __syncthreads();
  {
    int bij = 1;
    for (int i = lane; i < 256; i += 64) if (seen[i] != 1) bij = 0;
    if (!bij) fail = 1;
  }
  __syncthreads();
  if (lane == 0) *ok32p = fail ? 0 : 1;
}

// ---------------- weight conversion: row-major bf16 copies of W_ih, W_hh ----------
__global__ __launch_bounds__(256) void k_wconv(const void* __restrict__ W_ih,
                                               const void* __restrict__ W_hh,
                                               bf16* __restrict__ Wi_bf,
                                               bf16* __restrict__ Wh_bf,
                                               const int* __restrict__ flagp)
{
  const int isbf = *flagp;
  const int e = blockIdx.x * 256 + threadIdx.x;
  if (e < G4 * EMBD) Wi_bf[e] = (bf16)ldf(W_ih, e, isbf);
  if (e < G4 * HD)   Wh_bf[e] = (bf16)ldf(W_hh, e, isbf);
}

// ================= FUSED LSTM: all 20 steps in one launch (MFMA path) =============
// 32 nodes/block, 4 waves. Wave w owns gate cols {q*128 + w*32 + p*16 + n} for all
// four gates q (tiles (q,p), p in {0,1}). Since the (lane,reg)->(m,n) LUT is the same
// for every 16x16 tile, gates i/f/g/o of a (node,j) sit in the same lane+reg across
// acc tiles => cell state c stays in registers for the whole recurrence. h round-trips
// only through LDS (padded stride, conflict-free ds_read_b128). Bias folded into the
// MFMA accumulator init. HBM traffic: x_user once (+final h write) instead of
// 56MB/step of h/c state.
__global__ __launch_bounds__(256) void k_lstm_fused(
    const void* __restrict__ x_user, const bf16* __restrict__ Wi_bf,
    const bf16* __restrict__ Wh_bf, const void* __restrict__ b_ih,
    const void* __restrict__ b_hh, bf16* __restrict__ h_bf,
    const int* __restrict__ flagp, const int* __restrict__ ok32p,
    const int* __restrict__ lut32)
{
  if (!*ok32p) return;
  __shared__ bf16 xtile[32 * XPAD];   // 4.5 KB
  __shared__ bf16 h_lds[32 * HPAD];   // 8.5 KB
  const int isbf = *flagp;
  const int tid = threadIdx.x;
  const int n0 = blockIdx.x * 32;
  const int wave = tid >> 6, lane = tid & 63;
  const int mrow = lane & 15, quad = lane >> 4;
  const int jc0 = wave * 32;

  // (lane,reg) -> (m,n) decode (measured LUT)
  int lm[4], ln[4];
  #pragma unroll
  for (int reg = 0; reg < 4; ++reg) {
    const int v = lut32[lane * 4 + reg];
    lm[reg] = v >> 4; ln[reg] = v & 15;
  }
  // bias (b_ih + b_hh) at this lane's owned cols, as MFMA C-init fragments
  floatx4 binit[4][2];
  #pragma unroll
  for (int q = 0; q < 4; ++q)
    #pragma unroll
    for (int p = 0; p < 2; ++p)
      #pragma unroll
      for (int reg = 0; reg < 4; ++reg) {
        const int col = q * 128 + jc0 + p * 16 + ln[reg];
        binit[q][p][reg] = ldf(b_ih, col, isbf) + ldf(b_hh, col, isbf);
      }

  float creg[2][2][4];
  #pragma unroll
  for (int r = 0; r < 2; ++r)
    #pragma unroll
    for (int p = 0; p < 2; ++p)
      #pragma unroll
      for (int reg = 0; reg < 4; ++reg) creg[r][p][reg] = 0.f;

  for (int t = 0; t < T_STEPS; ++t) {
    // ---- stage x_t (fp32 or bf16 -> bf16 LDS) ----
    #pragma unroll
    for (int i = 0; i < 8; ++i) {
      const int idx = tid + i * 256;          // 0..2047
      const int n = idx >> 6, k = idx & 63;
      xtile[n * XPAD + k] =
          (bf16)ldf(x_user, (size_t)(n0 + n) * (T_STEPS * EMBD) + (size_t)t * EMBD + k, isbf);
    }
    __syncthreads();  // (A) xtile + prev-step h_lds visible to all waves

    floatx4 acc[2][4][2];
    #pragma unroll
    for (int r = 0; r < 2; ++r)
      #pragma unroll
      for (int q = 0; q < 4; ++q)
        #pragma unroll
        for (int p = 0; p < 2; ++p) acc[r][q][p] = binit[q][p];

    // ---- x_t @ W_ih^T (K=64) ----
    #pragma unroll
    for (int kc = 0; kc < 2; ++kc) {
      const int koff = kc * 32 + quad * 8;
      const bf16x8 a0 = *(const bf16x8*)(xtile + mrow * XPAD + koff);
      const bf16x8 a1 = *(const bf16x8*)(xtile + (16 + mrow) * XPAD + koff);
      #pragma unroll
      for (int q = 0; q < 4; ++q)
        #pragma unroll
        for (int p = 0; p < 2; ++p) {
          const bf16x8 b =
              *(const bf16x8*)(Wi_bf + (size_t)(q * 128 + jc0 + p * 16 + mrow) * EMBD + koff);
          acc[0][q][p] = __builtin_amdgcn_mfma_f32_16x16x32_bf16(a0, b, acc[0][q][p], 0, 0, 0);
          acc[1][q][p] = __builtin_amdgcn_mfma_f32_16x16x32_bf16(a1, b, acc[1][q][p], 0, 0, 0);
        }
    }
    // ---- h_{t-1} @ W_hh^T (K=128) ----
    if (t > 0) {
      #pragma unroll
      for (int kc = 0; kc < 4; ++kc) {
        const int koff = kc * 32 + quad * 8;
        const bf16x8 a0 = *(const bf16x8*)(h_lds + mrow * HPAD + koff);
        const bf16x8 a1 = *(const bf16x8*)(h_lds + (16 + mrow) * HPAD + koff);
        #pragma unroll
        for (int q = 0; q < 4; ++q)
          #pragma unroll
          for (int p = 0; p < 2; ++p) {
            const bf16x8 b =
                *(const bf16x8*)(Wh_bf + (size_t)(q * 128 + jc0 + p * 16 + mrow) * HD + koff);
            acc[0][q][p] = __builtin_amdgcn_mfma_f32_16x16x32_bf16(a0, b, acc[0][q][p], 0, 0, 0);
            acc[1][q][p] = __builtin_amdgcn_mfma_f32_16x16x32_bf16(a1, b, acc[1][q][p], 0, 0, 0);
          }
      }
    }
    __syncthreads();  // (B) all xtile / h_lds reads complete before overwrite

    // ---- cell update, fully in-register (gate order i,f,g,o) ----
    #pragma unroll
    for (int r = 0; r < 2; ++r)
      #pragma unroll
      for (int p = 0; p < 2; ++p)
        #pragma unroll
        for (int reg = 0; reg < 4; ++reg) {
          const float gi = acc[r][0][p][reg];
          const float gf = acc[r][1][p][reg];
          const float gg = acc[r][2][p][reg];
          const float go = acc[r][3][p][reg];
          const float cn = sigf(gf) * creg[r][p][reg] + sigf(gi) * tanhf(gg);
          creg[r][p][reg] = cn;
          const float hv = sigf(go) * tanhf(cn);
          const int nrow = r * 16 + lm[reg];
          const int col = jc0 + p * 16 + ln[reg];
          h_lds[nrow * HPAD + col] = (bf16)hv;
          if (t == T_STEPS - 1)
            h_bf[(size_t)(n0 + nrow) * HD + col] = (bf16)hv;
        }
    // next stage writes xtile only (disjoint from h_lds); reads wait on barrier (A)
  }
}

// ============ FUSED LSTM fallback: VALU, one launch (runs iff !ok32) =============
__global__ __launch_bounds__(256) void k_lstm_valu_fused(
    const void* __restrict__ x_user, const void* __restrict__ W_ih,
    const void* __restrict__ W_hh, const void* __restrict__ b_ih,
    const void* __restrict__ b_hh, bf16* __restrict__ h_bf,
    const int* __restrict__ flagp, const int* __restrict__ ok32p)
{
  if (*ok32p) return;
  __shared__ float gates[32 * G4];    // 64 KB; xl aliases first 2048 floats
  __shared__ float hl[32 * HD];       // 16 KB, persistent h
  __shared__ float cl[32 * HD];       // 16 KB, persistent c
  const int isbf = *flagp;
  const int tid = threadIdx.x;
  const int n0 = blockIdx.x * 32;
  float* xl = gates;
  #pragma unroll
  for (int i = 0; i < 16; ++i) { hl[tid + i * 256] = 0.f; cl[tid + i * 256] = 0.f; }
  __syncthreads();
  for (int t = 0; t < T_STEPS; ++t) {
    #pragma unroll
    for (int i = 0; i < 8; ++i) {
      const int idx = tid + i * 256;
      const int n = idx >> 6, k = idx & 63;
      xl[idx] = ldf(x_user, (size_t)(n0 + n) * (T_STEPS * EMBD) + (size_t)t * EMBD + k, isbf);
    }
    __syncthreads();
    const int col0 = tid, col1 = tid + 256;
    float acc0[32], acc1[32];
    #pragma unroll
    for (int n = 0; n < 32; ++n) { acc0[n] = 0.f; acc1[n] = 0.f; }
    for (int k = 0; k < EMBD; ++k) {
      const float w0 = ldf(W_ih, (size_t)col0 * EMBD + k, isbf);
      const float w1 = ldf(W_ih, (size_t)col1 * EMBD + k, isbf);
      #pragma unroll
      for (int n = 0; n < 32; ++n) {
        const float a = xl[n * EMBD + k];
        acc0[n] += a * w0; acc1[n] += a * w1;
      }
    }
    for (int k = 0; k < HD; ++k) {
      const float w0 = ldf(W_hh, (size_t)col0 * HD + k, isbf);
      const float w1 = ldf(W_hh, (size_t)col1 * HD + k, isbf);
      #pragma unroll
      for (int n = 0; n < 32; ++n) {
        const float a = hl[n * HD + k];
        acc0[n] += a * w0; acc1[n] += a * w1;
      }
    }
    __syncthreads();   // xl/hl reads done before gates overwrite
    #pragma unroll
    for (int n = 0; n < 32; ++n) {
      gates[n * G4 + col0] = acc0[n];
      gates[n * G4 + col1] = acc1[n];
    }
    __syncthreads();
    #pragma unroll
    for (int it = 0; it < 16; ++it) {
      const int lin = it * 256 + tid;
      const int nl = lin >> 7, j = lin & 127;
      const float gi = gates[nl * G4 + j]       + ldf(b_ih, j, isbf)       + ldf(b_hh, j, isbf);
      const float gf = gates[nl * G4 + 128 + j] + ldf(b_ih, 128 + j, isbf) + ldf(b_hh, 128 + j, isbf);
      const float gg = gates[nl * G4 + 256 + j] + ldf(b_ih, 256 + j, isbf) + ldf(b_hh, 256 + j, isbf);
      const float go = gates[nl * G4 + 384 + j] + ldf(b_ih, 384 + j, isbf) + ldf(b_hh, 384 + j, isbf);
      const float iv = sigf(gi), fv = sigf(gf), gv = tanhf(gg), ov = sigf(go);
      const float cnew = fv * cl[nl * HD + j] + iv * gv;
      cl[nl * HD + j] = cnew;
      const float hv = ov * tanhf(cnew);
      hl[nl * HD + j] = hv;
      if (t == T_STEPS - 1) h_bf[(size_t)(n0 + nl) * HD + j] = (bf16)hv;
    }
    __syncthreads();   // gate reads done & hl/cl updates visible before next step
  }
}

// ---------------- content linear ----------------
__global__ __launch_bounds__(256) void k_content(
    const void* __restrict__ x_content, const void* __restrict__ Wc,
    const void* __restrict__ bc, bf16* __restrict__ c_out,
    const int* __restrict__ flagp)
{
  __shared__ float xl[32 * EMBD];
  const int isbf = *flagp;
  const int tid = threadIdx.x;
  const int n0 = blockIdx.x * 32;
  #pragma unroll
  for (int i = 0; i < 8; ++i) {
    const int idx = tid + i * 256;
    xl[idx] = ldf(x_content, (size_t)n0 * EMBD + idx, isbf);
  }
  __syncthreads();
  const int jj = tid & 127, grp = tid >> 7;
  float acc[16];
  #pragma unroll
  for (int nn = 0; nn < 16; ++nn) acc[nn] = 0.f;
  for (int k = 0; k < EMBD; ++k) {
    const float w = ldf(Wc, (size_t)jj * EMBD + k, isbf);
    #pragma unroll
    for (int nn = 0; nn < 16; ++nn)
      acc[nn] += xl[(grp * 16 + nn) * EMBD + k] * w;
  }
  const float bj = ldf(bc, jj, isbf);
  #pragma unroll
  for (int nn = 0; nn < 16; ++nn)
    c_out[(size_t)(n0 + grp * 16 + nn) * HD + jj] = (bf16)(acc[nn] + bj);
}

// ================= CSR build =================
__global__ void k_count_int(const int* __restrict__ src, const int* __restrict__ dst,
                            int* __restrict__ deg_u, int* __restrict__ deg_c, int E)
{
  const int e = blockIdx.x * blockDim.x + threadIdx.x;
  if (e < E) {
    atomicAdd(deg_u + (src[e] & NMASK), 1);
    atomicAdd(deg_c + (dst[e] & NMASK), 1);
  }
}

__global__ __launch_bounds__(256) void k_scan(const int* __restrict__ deg,
                                              int* __restrict__ row, int* __restrict__ cur)
{
  __shared__ int part[256];
  const int tid = threadIdx.x;
  const int base = tid * 128;
  int s = 0;
  for (int i = 0; i < 128; ++i) s += deg[base + i];
  part[tid] = s;
  __syncthreads();
  if (tid == 0) {
    int a = 0;
    for (int i = 0; i < 256; ++i) { const int v = part[i]; part[i] = a; a += v; }
  }
  __syncthreads();
  int a = part[tid];
  for (int i = 0; i < 128; ++i) {
    row[base + i] = a; cur[base + i] = a;
    a += deg[base + i];
  }
  if (tid == 255) row[N_NODES] = a;
}

__global__ void k_build(const int* __restrict__ src, const int* __restrict__ dst,
                        int* __restrict__ cur_u, int* __restrict__ cur_c,
                        int* __restrict__ adj_u, int* __restrict__ adj_c, int E)
{
  const int e = blockIdx.x * blockDim.x + threadIdx.x;
  if (e < E) {
    const int s = src[e] & NMASK, d = dst[e] & NMASK;
    const int pc = atomicAdd(cur_c + d, 1);
    adj_c[pc] = s;
    const int pu = atomicAdd(cur_u + s, 1);
    adj_u[pu] = d;
  }
}

// gather-sum: agg[n][:] = sum over adj rows of feat. One wave per node.
__global__ __launch_bounds__(256) void k_gather(
    const bf16* __restrict__ feat, const int* __restrict__ adj,
    const int* __restrict__ row, float* __restrict__ agg)
{
  const int node = blockIdx.x * 4 + (threadIdx.x >> 6);
  const int lane = threadIdx.x & 63;
  const int beg = row[node], end = row[node + 1];
  float a0 = 0.f, a1 = 0.f;
  for (int p = beg; p < end; ++p) {
    const int s = adj[p];
    const bf16x2 v = *(const bf16x2*)(feat + (size_t)s * HD + 2 * lane);
    a0 += (float)v.x; a1 += (float)v.y;
  }
  float2* o = (float2*)(agg + (size_t)node * HD + 2 * lane);
  *o = float2{a0, a1};
}

// ---------------- SAGE linear ----------------
__global__ __launch_bounds__(256) void k_sage_lin(
    const float* __restrict__ agg, const int* __restrict__ cnt,
    const bf16* __restrict__ dstx,
    const void* __restrict__ Wl, const void* __restrict__ bl,
    const void* __restrict__ Wr, bf16* __restrict__ outp,
    const int* __restrict__ flagp)
{
  __shared__ float ml[32 * HD];
  __shared__ float xl[32 * HD];
  const int isbf = *flagp;
  const int tid = threadIdx.x;
  const int n0 = blockIdx.x * 32;
  #pragma unroll
  for (int i = 0; i < 16; ++i) {
    const int idx = tid + i * 256;
    const int n = idx >> 7;
    const float rc = 1.f / fmaxf((float)cnt[n0 + n], 1.f);
    ml[idx] = agg[(size_t)n0 * HD + idx] * rc;
    xl[idx] = (float)dstx[(size_t)n0 * HD + idx];
  }
  __syncthreads();
  const int jj = tid & 127, grp = tid >> 7;
  float acc[16];
  #pragma unroll
  for (int nn = 0; nn < 16; ++nn) acc[nn] = 0.f;
  for (int k = 0; k < HD; ++k) {
    const float wl = ldf(Wl, (size_t)jj * HD + k, isbf);
    const float wr = ldf(Wr, (size_t)jj * HD + k, isbf);
    #pragma unroll
    for (int nn = 0; nn < 16; ++nn)
      acc[nn] += ml[(grp * 16 + nn) * HD + k] * wl + xl[(grp * 16 + nn) * HD + k] * wr;
  }
  const float bj = ldf(bl, jj, isbf);
  #pragma unroll
  for (int nn = 0; nn < 16; ++nn)
    outp[(size_t)(n0 + grp * 16 + nn) * HD + jj] = (bf16)fmaxf(acc[nn] + bj, 0.f);
}

// ---------------- classifier hidden ----------------
__global__ __launch_bounds__(256) void k_cls(
    const bf16* __restrict__ u, const bf16* __restrict__ c,
    const void* __restrict__ W1, const void* __restrict__ b1,
    float* __restrict__ h1, const int* __restrict__ flagp)
{
  __shared__ float ul[32 * HD];
  __shared__ float cl[32 * HD];
  const int isbf = *flagp;
  const int tid = threadIdx.x;
  const int n0 = blockIdx.x * 32;
  #pragma unroll
  for (int i = 0; i < 16; ++i) {
    const int idx = tid + i * 256;
    ul[idx] = (float)u[(size_t)n0 * HD + idx];
    cl[idx] = (float)c[(size_t)n0 * HD + idx];
  }
  __syncthreads();
  const int jj = tid & 127, grp = tid >> 7;
  float acc[16];
  #pragma unroll
  for (int nn = 0; nn < 16; ++nn) acc[nn] = 0.f;
  for (int k = 0; k < HD; ++k) {
    const float wu = ldf(W1, (size_t)jj * 256 + k, isbf);
    const float wc = ldf(W1, (size_t)jj * 256 + 128 + k, isbf);
    #pragma unroll
    for (int nn = 0; nn < 16; ++nn)
      acc[nn] += ul[(grp * 16 + nn) * HD + k] * wu + cl[(grp * 16 + nn) * HD + k] * wc;
  }
  const float bj = ldf(b1, jj, isbf);
  #pragma unroll
  for (int nn = 0; nn < 16; ++nn)
    h1[(size_t)(n0 + grp * 16 + nn) * HD + jj] = fmaxf(acc[nn] + bj, 0.f);
}

// ---------------- output ----------------
__global__ __launch_bounds__(256) void k_out(
    const float* __restrict__ h1, const void* __restrict__ W2,
    const void* __restrict__ b2, void* __restrict__ out,
    const int* __restrict__ flagp)
{
  const int isbf = *flagp;
  const int wave = threadIdx.x >> 6, lane = threadIdx.x & 63;
  const int n = blockIdx.x * 4 + wave;
  float v = h1[(size_t)n * HD + lane] * ldf(W2, lane, isbf)
          + h1[(size_t)n * HD + 64 + lane] * ldf(W2, 64 + lane, isbf);
  #pragma unroll
  for (int off = 32; off > 0; off >>= 1) v += __shfl_down(v, off, 64);
  if (lane == 0) {
    const float r = sigf(v + ldf(b2, 0, isbf));
    if (isbf) ((bf16*)out)[n] = (bf16)r; else ((float*)out)[n] = r;
  }
}

extern "C" void kernel_launch(void* const* d_in, const int* in_sizes, int n_in,
                              void* d_out, int out_size, void* d_ws, size_t ws_size,
                              hipStream_t stream)
{
  const void* x_user    = d_in[0];
  const void* x_content = d_in[1];
  const int*  edge      = (const int*)d_in[2];
  const void* W_ih      = d_in[3];
  const void* W_hh      = d_in[4];
  const void* b_ih      = d_in[5];
  const void* b_hh      = d_in[6];
  const void* Wc        = d_in[7];
  const void* bc        = d_in[8];
  const void* Wl[2]     = {d_in[9],  d_in[12]};
  const void* blv[2]    = {d_in[10], d_in[13]};
  const void* Wr[2]     = {d_in[11], d_in[14]};
  const void* W1        = d_in[15];
  const void* b1        = d_in[16];
  const void* W2        = d_in[17];
  const void* b2        = d_in[18];

  const int E = in_sizes[2] / 2;
  const int* src = edge;
  const int* dst = edge + E;

  // ---- workspace layout (< 59 MB; >=80 MB proven available) ----
  const size_t MB = 1u << 20;
  char* ws = (char*)d_ws;
  float* agg  = (float*)ws;                  // 16 MB fp32: agg -> h1 (cstate gone)
  float* h1   = agg;
  bf16* u0 = (bf16*)(ws + 16 * MB);          // 8 MB: LSTM h / u ping
  bf16* c0 = (bf16*)(ws + 24 * MB);          // 8 MB
  bf16* u1 = (bf16*)(ws + 32 * MB);          // 8 MB
  bf16* c1 = (bf16*)(ws + 40 * MB);          // 8 MB
  int*  adj_c = (int*)(ws + 48 * MB);        // 4 MB
  int*  adj_u = (int*)(ws + 52 * MB);        // 4 MB
  int*  meta  = (int*)(ws + 56 * MB);
  int* deg_u = meta;                         // 32768
  int* deg_c = deg_u + N_NODES;              // 32768
  int* row_u = deg_c + N_NODES;              // 32769
  int* row_c = row_u + N_NODES + 1;          // 32769
  int* cur_u = row_c + N_NODES + 1;          // 32768
  int* cur_c = cur_u + N_NODES;              // 32768
  int* flag  = cur_c + N_NODES;
  int* ok32  = flag + 1;
  int* lut32 = flag + 4;                     // 256
  bf16* Wi_bf = (bf16*)(ws + 58 * MB);       // 512*64*2  = 64 KB
  bf16* Wh_bf = Wi_bf + G4 * EMBD;           // 512*128*2 = 128 KB
  unsigned short* fr = (unsigned short*)(ws + 58 * MB + 256 * 1024);  // probe scratch

  // ---- probes + weight conversion ----
  k_detect<<<1, 64, 0, stream>>>((const unsigned*)x_user, flag);
  k_probe<<<1, 64, 0, stream>>>(fr, lut32, ok32);
  k_wconv<<<(G4 * HD + 255) / 256, 256, 0, stream>>>(W_ih, W_hh, Wi_bf, Wh_bf, flag);

  // ---- LSTM: all 20 steps fused in one launch (mfma iff ok32, valu iff !ok32) ----
  k_lstm_fused<<<N_NODES / 32, 256, 0, stream>>>(x_user, Wi_bf, Wh_bf, b_ih, b_hh,
                                                 u0, flag, ok32, lut32);
  k_lstm_valu_fused<<<N_NODES / 32, 256, 0, stream>>>(x_user, W_ih, W_hh, b_ih, b_hh,
                                                      u0, flag, ok32);

  // ---- content embedding ----
  k_content<<<N_NODES / 32, 256, 0, stream>>>(x_content, Wc, bc, c0, flag);

  // ---- CSR build ----
  k_zero_int<<<(2 * N_NODES + 255) / 256, 256, 0, stream>>>(deg_u, 2 * N_NODES);
  k_count_int<<<(E + 255) / 256, 256, 0, stream>>>(src, dst, deg_u, deg_c, E);
  k_scan<<<1, 256, 0, stream>>>(deg_u, row_u, cur_u);
  k_scan<<<1, 256, 0, stream>>>(deg_c, row_c, cur_c);
  k_build<<<(E + 255) / 256, 256, 0, stream>>>(src, dst, cur_u, cur_c, adj_u, adj_c, E);

  // ---- 2 SAGE layers ----
  bf16* ui = u0; bf16* ci = c0; bf16* uo = u1; bf16* co = c1;
  for (int L = 0; L < 2; ++L) {
    k_gather<<<N_NODES / 4, 256, 0, stream>>>(ui, adj_c, row_c, agg);   // users -> content
    k_sage_lin<<<N_NODES / 32, 256, 0, stream>>>(agg, deg_c, ci, Wl[L], blv[L], Wr[L], co, flag);
    k_gather<<<N_NODES / 4, 256, 0, stream>>>(ci, adj_u, row_u, agg);   // content -> users
    k_sage_lin<<<N_NODES / 32, 256, 0, stream>>>(agg, deg_u, ui, Wl[L], blv[L], Wr[L], uo, flag);
    bf16* t1 = ui; ui = uo; uo = t1;
    bf16* t2 = ci; ci = co; co = t2;
  }

  // ---- classifier ----
  k_cls<<<N_NODES / 32, 256, 0, stream>>>(ui, ci, W1, b1, h1, flag);
  k_out<<<N_NODES / 4, 256, 0, stream>>>(h1, W2, b2, d_out, flag);
}

// Round 2
// 1716.589 us; speedup vs baseline: 1.6757x; 1.4933x over previous
//
#include <hip/hip_runtime.h>
#include <hip/hip_bf16.h>

// GNNRecommender: LSTM(20) + content linear + 2x bipartite SAGE (CSR gather) + classifier.
// Round 10: LSTM latency fix. Round-9 measured: k_lstm_fused 1018us, MfmaUtil 5%,
// VALUBusy 19%, Occupancy 12%, hbm 1.2% => pure latency stalls. Causes: (a) 48 weight
// B-fragment L2 loads per wave per STEP, (b) scalar 4B x-staging waited on behind a
// barrier every step, (c) libm tanhf. Now: 16 gate-cols/wave (4 waves, 16 nodes/block,
// grid 2048), weights register-resident (96 VGPR, loaded ONCE), x_t+1 prefetched as
// float4 under step t's compute, fast tanh via __expf. Same MFMA/LUT math otherwise.

typedef __bf16 bf16;
typedef __bf16 bf16x2 __attribute__((ext_vector_type(2)));
typedef __bf16 bf16x4 __attribute__((ext_vector_type(4)));
typedef __bf16 bf16x8 __attribute__((ext_vector_type(8)));
typedef float floatx4 __attribute__((ext_vector_type(4)));

#define N_NODES 32768
#define NMASK 32767
#define T_STEPS 20
#define EMBD 64
#define HD 128
#define G4 512   // 4*H gate width
#define LB 16    // nodes per LSTM block
#define XPAD 72  // xtile row stride (bf16): 4(mrow+quad)+16kc bank spread, conflict-light
#define HPAD 136 // h_lds row stride (bf16): same spread property, 16B aligned rows

__device__ __forceinline__ float sigf(float x) { return 1.f / (1.f + __expf(-x)); }
// fast tanh: 1 - 2/(e^{2x}+1); exact at +-inf, ~1e-6 rel err via v_exp
__device__ __forceinline__ float tanh_fast(float x) {
  const float e = __expf(2.f * x);
  return 1.f - 2.f / (e + 1.f);
}

__device__ __forceinline__ float ldf(const void* p, size_t i, int isbf) {
  return isbf ? (float)((const bf16*)p)[i] : ((const float*)p)[i];
}

// exact-integer probe matrices (small ints => exact in bf16 and fp32)
__device__ __forceinline__ float A3f(int m, int k) { return (float)((m * 37 + k * 11) % 13 - 6); }
__device__ __forceinline__ float B3f(int k, int n) { return (float)((k * 7 + n * 29) % 11 - 5); }
__device__ __forceinline__ unsigned short bfb(float f) {
  return (unsigned short)(__float_as_uint(f) >> 16);
}

// ---------------- dtype probe: flag=1 bf16, 0 fp32 ----------------
__global__ void k_detect(const unsigned* __restrict__ x, int* __restrict__ flag)
{
  if (threadIdx.x == 0 && blockIdx.x == 0) {
    int cnt = 0;
    for (int i = 0; i < 256; ++i) {
      const unsigned w = x[i];
      const unsigned e0 = (w >> 7) & 0xffu;
      const unsigned e1 = (w >> 23) & 0xffu;
      const bool ok0 = (e0 >= 90u && e0 <= 141u) || ((w & 0x7fffu) == 0u);
      const bool ok1 = (e1 >= 90u && e1 <= 141u) || (((w >> 16) & 0x7fffu) == 0u);
      if (ok0 && ok1) ++cnt;
    }
    *flag = (cnt >= 200) ? 1 : 0;
  }
}

__global__ __launch_bounds__(256) void k_zero_int(int* __restrict__ p, int n)
{
  const int i = blockIdx.x * 256 + threadIdx.x;
  if (i < n) p[i] = 0;
}

// ================= MFMA probe (verified working; ok32=1 measured) =================
__global__ __launch_bounds__(64) void k_probe(
    unsigned short* __restrict__ fr, int* __restrict__ lut32, int* __restrict__ ok32p)
{
  __shared__ int seen[256];
  __shared__ int fail;
  const int lane = threadIdx.x;
  const int mrow = lane & 15, quad = lane >> 4;
  const floatx4 vz = {0.f, 0.f, 0.f, 0.f};

  unsigned short* fa1 = fr + 0 * 512;
  unsigned short* fb1 = fr + 1 * 512;
  unsigned short* fa2 = fr + 2 * 512;
  unsigned short* fb2 = fr + 3 * 512;
  unsigned short* fa3 = fr + 4 * 512;
  unsigned short* fb3 = fr + 5 * 512;
  for (int j = 0; j < 8; ++j) {
    fa1[lane * 8 + j] = bfb((float)(mrow + 1));
    fb1[lane * 8 + j] = bfb(1.0f);
    fa2[lane * 8 + j] = bfb(1.0f);
    fb2[lane * 8 + j] = bfb((float)(mrow + 1));
    fa3[lane * 8 + j] = bfb(A3f(mrow, quad * 8 + j));
    fb3[lane * 8 + j] = bfb(B3f(quad * 8 + j, mrow));
  }
  for (int i = lane; i < 256; i += 64) seen[i] = 0;
  if (lane == 0) fail = 0;
  __syncthreads();
  {
    bf16x8 a1 = *(const bf16x8*)(fa1 + lane * 8);
    bf16x8 b1 = *(const bf16x8*)(fb1 + lane * 8);
    bf16x8 a2 = *(const bf16x8*)(fa2 + lane * 8);
    bf16x8 b2 = *(const bf16x8*)(fb2 + lane * 8);
    bf16x8 a3 = *(const bf16x8*)(fa3 + lane * 8);
    bf16x8 b3 = *(const bf16x8*)(fb3 + lane * 8);
    floatx4 r1 = __builtin_amdgcn_mfma_f32_16x16x32_bf16(a1, b1, vz, 0, 0, 0);
    floatx4 r2 = __builtin_amdgcn_mfma_f32_16x16x32_bf16(a2, b2, vz, 0, 0, 0);
    floatx4 r3 = __builtin_amdgcn_mfma_f32_16x16x32_bf16(a3, b3, vz, 0, 0, 0);
    #pragma unroll
    for (int reg = 0; reg < 4; ++reg) {
      const int m = __float2int_rn(r1[reg] * (1.f / 32.f)) - 1;
      const int n = __float2int_rn(r2[reg] * (1.f / 32.f)) - 1;
      bool good = (m >= 0 && m < 16 && n >= 0 && n < 16)
               && fabsf(r1[reg] - 32.f * (m + 1)) < 0.5f
               && fabsf(r2[reg] - 32.f * (n + 1)) < 0.5f;
      if (good) {
        float c3 = 0.f;
        for (int k = 0; k < 32; ++k) c3 += A3f(m, k) * B3f(k, n);
        good = fabsf(r3[reg] - c3) < 0.5f;
      }
      if (good) {
        atomicAdd(&seen[m * 16 + n], 1);
        lut32[lane * 4 + reg] = (m << 4) | n;
      } else fail = 1;
    }
  }
  __syncthreads();
  {
    int bij = 1;
    for (int i = lane; i < 256; i += 64) if (seen[i] != 1) bij = 0;
    if (!bij) fail = 1;
  }
  __syncthreads();
  if (lane == 0) *ok32p = fail ? 0 : 1;
}

// ---------------- weight conversion: row-major bf16 copies of W_ih, W_hh ----------
__global__ __launch_bounds__(256) void k_wconv(const void* __restrict__ W_ih,
                                               const void* __restrict__ W_hh,
                                               bf16* __restrict__ Wi_bf,
                                               bf16* __restrict__ Wh_bf,
                                               const int* __restrict__ flagp)
{
  const int isbf = *flagp;
  const int e = blockIdx.x * 256 + threadIdx.x;
  if (e < G4 * EMBD) Wi_bf[e] = (bf16)ldf(W_ih, e, isbf);
  if (e < G4 * HD)   Wh_bf[e] = (bf16)ldf(W_hh, e, isbf);
}

// ================= FUSED LSTM: all 20 steps, one launch (MFMA path) ===============
// 16 nodes/block, 4 waves, wave w owns gate cols {q*128 + w*16 + n : q=0..3}.
// Weights register-resident (loaded once): Wi 8 frags + Wh 16 frags per lane.
// x_{t+1} prefetched as float4 under step t's compute. Cell state c in registers
// (LUT makes i/f/g/o of a (node,j) share lane+reg across the 4 q-tiles).
// h round-trips through padded LDS only. 2 barriers/step.
__global__ __launch_bounds__(256) void k_lstm_fused(
    const void* __restrict__ x_user, const bf16* __restrict__ Wi_bf,
    const bf16* __restrict__ Wh_bf, const void* __restrict__ b_ih,
    const void* __restrict__ b_hh, bf16* __restrict__ h_bf,
    const int* __restrict__ flagp, const int* __restrict__ ok32p,
    const int* __restrict__ lut32)
{
  if (!*ok32p) return;
  __shared__ bf16 xtile[LB * XPAD];   // 2.25 KB
  __shared__ bf16 h_lds[LB * HPAD];   // 4.25 KB
  const int isbf = *flagp;
  const int tid = threadIdx.x;
  const int n0 = blockIdx.x * LB;
  const int wave = tid >> 6, lane = tid & 63;
  const int mrow = lane & 15, quad = lane >> 4;
  const int jc0 = wave * 16;
  const int koq = quad * 8;

  // (lane,reg) -> (m,n) decode (measured LUT)
  int lm[4], ln[4];
  #pragma unroll
  for (int reg = 0; reg < 4; ++reg) {
    const int v = lut32[lane * 4 + reg];
    lm[reg] = v >> 4; ln[reg] = v & 15;
  }

  // ---- register-resident weight fragments (loaded ONCE) ----
  bf16x8 wfi[2][4];   // [kc][q] : x-path, K=64
  #pragma unroll
  for (int kc = 0; kc < 2; ++kc)
    #pragma unroll
    for (int q = 0; q < 4; ++q)
      wfi[kc][q] = *(const bf16x8*)(Wi_bf + (size_t)(q * 128 + jc0 + mrow) * EMBD + kc * 32 + koq);
  bf16x8 wfh[4][4];   // [kc][q] : h-path, K=128
  #pragma unroll
  for (int kc = 0; kc < 4; ++kc)
    #pragma unroll
    for (int q = 0; q < 4; ++q)
      wfh[kc][q] = *(const bf16x8*)(Wh_bf + (size_t)(q * 128 + jc0 + mrow) * HD + kc * 32 + koq);

  // bias (b_ih + b_hh) at this lane's owned cols, as MFMA C-init fragments
  floatx4 binit[4];
  #pragma unroll
  for (int q = 0; q < 4; ++q)
    #pragma unroll
    for (int reg = 0; reg < 4; ++reg) {
      const int col = q * 128 + jc0 + ln[reg];
      binit[q][reg] = ldf(b_ih, col, isbf) + ldf(b_hh, col, isbf);
    }

  float creg[4] = {0.f, 0.f, 0.f, 0.f};

  // ---- x prefetch: thread owns node xn, cols [xk, xk+4) ----
  const int xn = tid >> 4, xk = (tid & 15) * 4;
  const size_t xbase = (size_t)(n0 + xn) * (T_STEPS * EMBD) + xk;
  float xf0, xf1, xf2, xf3;
  {
    if (isbf) {
      const bf16x4 v = *(const bf16x4*)((const bf16*)x_user + xbase);
      xf0 = (float)v[0]; xf1 = (float)v[1]; xf2 = (float)v[2]; xf3 = (float)v[3];
    } else {
      const float4 v = *(const float4*)((const float*)x_user + xbase);
      xf0 = v.x; xf1 = v.y; xf2 = v.z; xf3 = v.w;
    }
  }

  for (int t = 0; t < T_STEPS; ++t) {
    // (a) commit prefetched x_t to LDS (prev iter's xtile readers done at barrier (e))
    {
      bf16x4 xv;
      xv[0] = (bf16)xf0; xv[1] = (bf16)xf1; xv[2] = (bf16)xf2; xv[3] = (bf16)xf3;
      *(bf16x4*)(xtile + xn * XPAD + xk) = xv;
    }
    // (b) issue prefetch of x_{t+1}; latency hides under this step's MFMA+epilogue
    if (t + 1 < T_STEPS) {
      const size_t bb = xbase + (size_t)(t + 1) * EMBD;
      if (isbf) {
        const bf16x4 v = *(const bf16x4*)((const bf16*)x_user + bb);
        xf0 = (float)v[0]; xf1 = (float)v[1]; xf2 = (float)v[2]; xf3 = (float)v[3];
      } else {
        const float4 v = *(const float4*)((const float*)x_user + bb);
        xf0 = v.x; xf1 = v.y; xf2 = v.z; xf3 = v.w;
      }
    }
    __syncthreads();   // (c) xtile(t) + h_lds(t-1) visible to all waves

    floatx4 acc[4];
    #pragma unroll
    for (int q = 0; q < 4; ++q) acc[q] = binit[q];

    // ---- x_t @ W_ih^T (K=64) ----
    #pragma unroll
    for (int kc = 0; kc < 2; ++kc) {
      const bf16x8 a = *(const bf16x8*)(xtile + mrow * XPAD + kc * 32 + koq);
      #pragma unroll
      for (int q = 0; q < 4; ++q)
        acc[q] = __builtin_amdgcn_mfma_f32_16x16x32_bf16(a, wfi[kc][q], acc[q], 0, 0, 0);
    }
    // ---- h_{t-1} @ W_hh^T (K=128) ----
    if (t > 0) {
      #pragma unroll
      for (int kc = 0; kc < 4; ++kc) {
        const bf16x8 a = *(const bf16x8*)(h_lds + mrow * HPAD + kc * 32 + koq);
        #pragma unroll
        for (int q = 0; q < 4; ++q)
          acc[q] = __builtin_amdgcn_mfma_f32_16x16x32_bf16(a, wfh[kc][q], acc[q], 0, 0, 0);
      }
    }
    __syncthreads();   // (e) all xtile/h_lds reads complete before overwrite

    // ---- cell update, in-register (gate order i,f,g,o) ----
    #pragma unroll
    for (int reg = 0; reg < 4; ++reg) {
      const float gi = acc[0][reg];
      const float gf = acc[1][reg];
      const float gg = acc[2][reg];
      const float go = acc[3][reg];
      const float cn = sigf(gf) * creg[reg] + sigf(gi) * tanh_fast(gg);
      creg[reg] = cn;
      const float hv = sigf(go) * tanh_fast(cn);
      const int col = jc0 + ln[reg];
      h_lds[lm[reg] * HPAD + col] = (bf16)hv;
      if (t == T_STEPS - 1)
        h_bf[(size_t)(n0 + lm[reg]) * HD + col] = (bf16)hv;
    }
  }
}

// ============ FUSED LSTM fallback: VALU, one launch (runs iff !ok32) =============
__global__ __launch_bounds__(256) void k_lstm_valu_fused(
    const void* __restrict__ x_user, const void* __restrict__ W_ih,
    const void* __restrict__ W_hh, const void* __restrict__ b_ih,
    const void* __restrict__ b_hh, bf16* __restrict__ h_bf,
    const int* __restrict__ flagp, const int* __restrict__ ok32p)
{
  if (*ok32p) return;
  __shared__ float gates[32 * G4];    // 64 KB; xl aliases first 2048 floats
  __shared__ float hl[32 * HD];       // 16 KB, persistent h
  __shared__ float cl[32 * HD];       // 16 KB, persistent c
  const int isbf = *flagp;
  const int tid = threadIdx.x;
  const int n0 = blockIdx.x * 32;
  float* xl = gates;
  #pragma unroll
  for (int i = 0; i < 16; ++i) { hl[tid + i * 256] = 0.f; cl[tid + i * 256] = 0.f; }
  __syncthreads();
  for (int t = 0; t < T_STEPS; ++t) {
    #pragma unroll
    for (int i = 0; i < 8; ++i) {
      const int idx = tid + i * 256;
      const int n = idx >> 6, k = idx & 63;
      xl[idx] = ldf(x_user, (size_t)(n0 + n) * (T_STEPS * EMBD) + (size_t)t * EMBD + k, isbf);
    }
    __syncthreads();
    const int col0 = tid, col1 = tid + 256;
    float acc0[32], acc1[32];
    #pragma unroll
    for (int n = 0; n < 32; ++n) { acc0[n] = 0.f; acc1[n] = 0.f; }
    for (int k = 0; k < EMBD; ++k) {
      const float w0 = ldf(W_ih, (size_t)col0 * EMBD + k, isbf);
      const float w1 = ldf(W_ih, (size_t)col1 * EMBD + k, isbf);
      #pragma unroll
      for (int n = 0; n < 32; ++n) {
        const float a = xl[n * EMBD + k];
        acc0[n] += a * w0; acc1[n] += a * w1;
      }
    }
    for (int k = 0; k < HD; ++k) {
      const float w0 = ldf(W_hh, (size_t)col0 * HD + k, isbf);
      const float w1 = ldf(W_hh, (size_t)col1 * HD + k, isbf);
      #pragma unroll
      for (int n = 0; n < 32; ++n) {
        const float a = hl[n * HD + k];
        acc0[n] += a * w0; acc1[n] += a * w1;
      }
    }
    __syncthreads();   // xl/hl reads done before gates overwrite
    #pragma unroll
    for (int n = 0; n < 32; ++n) {
      gates[n * G4 + col0] = acc0[n];
      gates[n * G4 + col1] = acc1[n];
    }
    __syncthreads();
    #pragma unroll
    for (int it = 0; it < 16; ++it) {
      const int lin = it * 256 + tid;
      const int nl = lin >> 7, j = lin & 127;
      const float gi = gates[nl * G4 + j]       + ldf(b_ih, j, isbf)       + ldf(b_hh, j, isbf);
      const float gf = gates[nl * G4 + 128 + j] + ldf(b_ih, 128 + j, isbf) + ldf(b_hh, 128 + j, isbf);
      const float gg = gates[nl * G4 + 256 + j] + ldf(b_ih, 256 + j, isbf) + ldf(b_hh, 256 + j, isbf);
      const float go = gates[nl * G4 + 384 + j] + ldf(b_ih, 384 + j, isbf) + ldf(b_hh, 384 + j, isbf);
      const float iv = sigf(gi), fv = sigf(gf), gv = tanhf(gg), ov = sigf(go);
      const float cnew = fv * cl[nl * HD + j] + iv * gv;
      cl[nl * HD + j] = cnew;
      const float hv = ov * tanhf(cnew);
      hl[nl * HD + j] = hv;
      if (t == T_STEPS - 1) h_bf[(size_t)(n0 + nl) * HD + j] = (bf16)hv;
    }
    __syncthreads();   // gate reads done & hl/cl updates visible before next step
  }
}

// ---------------- content linear ----------------
__global__ __launch_bounds__(256) void k_content(
    const void* __restrict__ x_content, const void* __restrict__ Wc,
    const void* __restrict__ bc, bf16* __restrict__ c_out,
    const int* __restrict__ flagp)
{
  __shared__ float xl[32 * EMBD];
  const int isbf = *flagp;
  const int tid = threadIdx.x;
  const int n0 = blockIdx.x * 32;
  #pragma unroll
  for (int i = 0; i < 8; ++i) {
    const int idx = tid + i * 256;
    xl[idx] = ldf(x_content, (size_t)n0 * EMBD + idx, isbf);
  }
  __syncthreads();
  const int jj = tid & 127, grp = tid >> 7;
  float acc[16];
  #pragma unroll
  for (int nn = 0; nn < 16; ++nn) acc[nn] = 0.f;
  for (int k = 0; k < EMBD; ++k) {
    const float w = ldf(Wc, (size_t)jj * EMBD + k, isbf);
    #pragma unroll
    for (int nn = 0; nn < 16; ++nn)
      acc[nn] += xl[(grp * 16 + nn) * EMBD + k] * w;
  }
  const float bj = ldf(bc, jj, isbf);
  #pragma unroll
  for (int nn = 0; nn < 16; ++nn)
    c_out[(size_t)(n0 + grp * 16 + nn) * HD + jj] = (bf16)(acc[nn] + bj);
}

// ================= CSR build =================
__global__ void k_count_int(const int* __restrict__ src, const int* __restrict__ dst,
                            int* __restrict__ deg_u, int* __restrict__ deg_c, int E)
{
  const int e = blockIdx.x * blockDim.x + threadIdx.x;
  if (e < E) {
    atomicAdd(deg_u + (src[e] & NMASK), 1);
    atomicAdd(deg_c + (dst[e] & NMASK), 1);
  }
}

__global__ __launch_bounds__(256) void k_scan(const int* __restrict__ deg,
                                              int* __restrict__ row, int* __restrict__ cur)
{
  __shared__ int part[256];
  const int tid = threadIdx.x;
  const int base = tid * 128;
  int s = 0;
  for (int i = 0; i < 128; ++i) s += deg[base + i];
  part[tid] = s;
  __syncthreads();
  if (tid == 0) {
    int a = 0;
    for (int i = 0; i < 256; ++i) { const int v = part[i]; part[i] = a; a += v; }
  }
  __syncthreads();
  int a = part[tid];
  for (int i = 0; i < 128; ++i) {
    row[base + i] = a; cur[base + i] = a;
    a += deg[base + i];
  }
  if (tid == 255) row[N_NODES] = a;
}

__global__ void k_build(const int* __restrict__ src, const int* __restrict__ dst,
                        int* __restrict__ cur_u, int* __restrict__ cur_c,
                        int* __restrict__ adj_u, int* __restrict__ adj_c, int E)
{
  const int e = blockIdx.x * blockDim.x + threadIdx.x;
  if (e < E) {
    const int s = src[e] & NMASK, d = dst[e] & NMASK;
    const int pc = atomicAdd(cur_c + d, 1);
    adj_c[pc] = s;
    const int pu = atomicAdd(cur_u + s, 1);
    adj_u[pu] = d;
  }
}

// gather-sum: agg[n][:] = sum over adj rows of feat. One wave per node.
__global__ __launch_bounds__(256) void k_gather(
    const bf16* __restrict__ feat, const int* __restrict__ adj,
    const int* __restrict__ row, float* __restrict__ agg)
{
  const int node = blockIdx.x * 4 + (threadIdx.x >> 6);
  const int lane = threadIdx.x & 63;
  const int beg = row[node], end = row[node + 1];
  float a0 = 0.f, a1 = 0.f;
  for (int p = beg; p < end; ++p) {
    const int s = adj[p];
    const bf16x2 v = *(const bf16x2*)(feat + (size_t)s * HD + 2 * lane);
    a0 += (float)v.x; a1 += (float)v.y;
  }
  float2* o = (float2*)(agg + (size_t)node * HD + 2 * lane);
  *o = float2{a0, a1};
}

// ---------------- SAGE linear ----------------
__global__ __launch_bounds__(256) void k_sage_lin(
    const float* __restrict__ agg, const int* __restrict__ cnt,
    const bf16* __restrict__ dstx,
    const void* __restrict__ Wl, const void* __restrict__ bl,
    const void* __restrict__ Wr, bf16* __restrict__ outp,
    const int* __restrict__ flagp)
{
  __shared__ float ml[32 * HD];
  __shared__ float xl[32 * HD];
  const int isbf = *flagp;
  const int tid = threadIdx.x;
  const int n0 = blockIdx.x * 32;
  #pragma unroll
  for (int i = 0; i < 16; ++i) {
    const int idx = tid + i * 256;
    const int n = idx >> 7;
    const float rc = 1.f / fmaxf((float)cnt[n0 + n], 1.f);
    ml[idx] = agg[(size_t)n0 * HD + idx] * rc;
    xl[idx] = (float)dstx[(size_t)n0 * HD + idx];
  }
  __syncthreads();
  const int jj = tid & 127, grp = tid >> 7;
  float acc[16];
  #pragma unroll
  for (int nn = 0; nn < 16; ++nn) acc[nn] = 0.f;
  for (int k = 0; k < HD; ++k) {
    const float wl = ldf(Wl, (size_t)jj * HD + k, isbf);
    const float wr = ldf(Wr, (size_t)jj * HD + k, isbf);
    #pragma unroll
    for (int nn = 0; nn < 16; ++nn)
      acc[nn] += ml[(grp * 16 + nn) * HD + k] * wl + xl[(grp * 16 + nn) * HD + k] * wr;
  }
  const float bj = ldf(bl, jj, isbf);
  #pragma unroll
  for (int nn = 0; nn < 16; ++nn)
    outp[(size_t)(n0 + grp * 16 + nn) * HD + jj] = (bf16)fmaxf(acc[nn] + bj, 0.f);
}

// ---------------- classifier hidden ----------------
__global__ __launch_bounds__(256) void k_cls(
    const bf16* __restrict__ u, const bf16* __restrict__ c,
    const void* __restrict__ W1, const void* __restrict__ b1,
    float* __restrict__ h1, const int* __restrict__ flagp)
{
  __shared__ float ul[32 * HD];
  __shared__ float cl[32 * HD];
  const int isbf = *flagp;
  const int tid = threadIdx.x;
  const int n0 = blockIdx.x * 32;
  #pragma unroll
  for (int i = 0; i < 16; ++i) {
    const int idx = tid + i * 256;
    ul[idx] = (float)u[(size_t)n0 * HD + idx];
    cl[idx] = (float)c[(size_t)n0 * HD + idx];
  }
  __syncthreads();
  const int jj = tid & 127, grp = tid >> 7;
  float acc[16];
  #pragma unroll
  for (int nn = 0; nn < 16; ++nn) acc[nn] = 0.f;
  for (int k = 0; k < HD; ++k) {
    const float wu = ldf(W1, (size_t)jj * 256 + k, isbf);
    const float wc = ldf(W1, (size_t)jj * 256 + 128 + k, isbf);
    #pragma unroll
    for (int nn = 0; nn < 16; ++nn)
      acc[nn] += ul[(grp * 16 + nn) * HD + k] * wu + cl[(grp * 16 + nn) * HD + k] * wc;
  }
  const float bj = ldf(b1, jj, isbf);
  #pragma unroll
  for (int nn = 0; nn < 16; ++nn)
    h1[(size_t)(n0 + grp * 16 + nn) * HD + jj] = fmaxf(acc[nn] + bj, 0.f);
}

// ---------------- output ----------------
__global__ __launch_bounds__(256) void k_out(
    const float* __restrict__ h1, const void* __restrict__ W2,
    const void* __restrict__ b2, void* __restrict__ out,
    const int* __restrict__ flagp)
{
  const int isbf = *flagp;
  const int wave = threadIdx.x >> 6, lane = threadIdx.x & 63;
  const int n = blockIdx.x * 4 + wave;
  float v = h1[(size_t)n * HD + lane] * ldf(W2, lane, isbf)
          + h1[(size_t)n * HD + 64 + lane] * ldf(W2, 64 + lane, isbf);
  #pragma unroll
  for (int off = 32; off > 0; off >>= 1) v += __shfl_down(v, off, 64);
  if (lane == 0) {
    const float r = sigf(v + ldf(b2, 0, isbf));
    if (isbf) ((bf16*)out)[n] = (bf16)r; else ((float*)out)[n] = r;
  }
}

extern "C" void kernel_launch(void* const* d_in, const int* in_sizes, int n_in,
                              void* d_out, int out_size, void* d_ws, size_t ws_size,
                              hipStream_t stream)
{
  const void* x_user    = d_in[0];
  const void* x_content = d_in[1];
  const int*  edge      = (const int*)d_in[2];
  const void* W_ih      = d_in[3];
  const void* W_hh      = d_in[4];
  const void* b_ih      = d_in[5];
  const void* b_hh      = d_in[6];
  const void* Wc        = d_in[7];
  const void* bc        = d_in[8];
  const void* Wl[2]     = {d_in[9],  d_in[12]};
  const void* blv[2]    = {d_in[10], d_in[13]};
  const void* Wr[2]     = {d_in[11], d_in[14]};
  const void* W1        = d_in[15];
  const void* b1        = d_in[16];
  const void* W2        = d_in[17];
  const void* b2        = d_in[18];

  const int E = in_sizes[2] / 2;
  const int* src = edge;
  const int* dst = edge + E;

  // ---- workspace layout (< 59 MB; >=80 MB proven available) ----
  const size_t MB = 1u << 20;
  char* ws = (char*)d_ws;
  float* agg  = (float*)ws;                  // 16 MB fp32: agg -> h1
  float* h1   = agg;
  bf16* u0 = (bf16*)(ws + 16 * MB);          // 8 MB: LSTM h / u ping
  bf16* c0 = (bf16*)(ws + 24 * MB);          // 8 MB
  bf16* u1 = (bf16*)(ws + 32 * MB);          // 8 MB
  bf16* c1 = (bf16*)(ws + 40 * MB);          // 8 MB
  int*  adj_c = (int*)(ws + 48 * MB);        // 4 MB
  int*  adj_u = (int*)(ws + 52 * MB);        // 4 MB
  int*  meta  = (int*)(ws + 56 * MB);
  int* deg_u = meta;                         // 32768
  int* deg_c = deg_u + N_NODES;              // 32768
  int* row_u = deg_c + N_NODES;              // 32769
  int* row_c = row_u + N_NODES + 1;          // 32769
  int* cur_u = row_c + N_NODES + 1;          // 32768
  int* cur_c = cur_u + N_NODES;              // 32768
  int* flag  = cur_c + N_NODES;
  int* ok32  = flag + 1;
  int* lut32 = flag + 4;                     // 256
  bf16* Wi_bf = (bf16*)(ws + 58 * MB);       // 512*64*2  = 64 KB
  bf16* Wh_bf = Wi_bf + G4 * EMBD;           // 512*128*2 = 128 KB
  unsigned short* fr = (unsigned short*)(ws + 58 * MB + 256 * 1024);  // probe scratch

  // ---- probes + weight conversion ----
  k_detect<<<1, 64, 0, stream>>>((const unsigned*)x_user, flag);
  k_probe<<<1, 64, 0, stream>>>(fr, lut32, ok32);
  k_wconv<<<(G4 * HD + 255) / 256, 256, 0, stream>>>(W_ih, W_hh, Wi_bf, Wh_bf, flag);

  // ---- LSTM: all 20 steps fused in one launch (mfma iff ok32, valu iff !ok32) ----
  k_lstm_fused<<<N_NODES / LB, 256, 0, stream>>>(x_user, Wi_bf, Wh_bf, b_ih, b_hh,
                                                 u0, flag, ok32, lut32);
  k_lstm_valu_fused<<<N_NODES / 32, 256, 0, stream>>>(x_user, W_ih, W_hh, b_ih, b_hh,
                                                      u0, flag, ok32);

  // ---- content embedding ----
  k_content<<<N_NODES / 32, 256, 0, stream>>>(x_content, Wc, bc, c0, flag);

  // ---- CSR build ----
  k_zero_int<<<(2 * N_NODES + 255) / 256, 256, 0, stream>>>(deg_u, 2 * N_NODES);
  k_count_int<<<(E + 255) / 256, 256, 0, stream>>>(src, dst, deg_u, deg_c, E);
  k_scan<<<1, 256, 0, stream>>>(deg_u, row_u, cur_u);
  k_scan<<<1, 256, 0, stream>>>(deg_c, row_c, cur_c);
  k_build<<<(E + 255) / 256, 256, 0, stream>>>(src, dst, cur_u, cur_c, adj_u, adj_c, E);

  // ---- 2 SAGE layers ----
  bf16* ui = u0; bf16* ci = c0; bf16* uo = u1; bf16* co = c1;
  for (int L = 0; L < 2; ++L) {
    k_gather<<<N_NODES / 4, 256, 0, stream>>>(ui, adj_c, row_c, agg);   // users -> content
    k_sage_lin<<<N_NODES / 32, 256, 0, stream>>>(agg, deg_c, ci, Wl[L], blv[L], Wr[L], co, flag);
    k_gather<<<N_NODES / 4, 256, 0, stream>>>(ci, adj_u, row_u, agg);   // content -> users
    k_sage_lin<<<N_NODES / 32, 256, 0, stream>>>(agg, deg_u, ui, Wl[L], blv[L], Wr[L], uo, flag);
    bf16* t1 = ui; ui = uo; uo = t1;
    bf16* t2 = ci; ci = co; co = t2;
  }

  // ---- classifier ----
  k_cls<<<N_NODES / 32, 256, 0, stream>>>(ui, ci, W1, b1, h1, flag);
  k_out<<<N_NODES / 4, 256, 0, stream>>>(h1, W2, b2, d_out, flag);
}